// Round 14
// baseline (85.932 us; speedup 1.0000x reference)
//
#include <hip/hip_runtime.h>

#define DIM_W 160
#define DIM_H 192
#define DIM_D 160
#define DIM_B 2

constexpr int TW = 16;      // output tile width
constexpr int TH = 32;      // output tile height (P=2 px/thread in H)
constexpr int CH = 19;      // depth outputs per chunk: 27 slices = 14 pairs (28th masked)
constexpr int NCH = 9;      // ceil(160/19)
constexpr int RH = 40;      // region rows
constexpr int RWDS = 24;    // words per region row (4 + 16 + 4 halo)
constexpr float INV_K = 1.0f / 729.0f;
constexpr double NTOT = 9830400.0;

typedef unsigned int u32;
typedef __attribute__((address_space(1))) const u32 gu32;
typedef __attribute__((address_space(3))) u32 lu32;
typedef _Float16 h2 __attribute__((ext_vector_type(2)));

__global__ void init_kernel(float* out, float* ws) {
    out[0] = 0.0f;
    ws[0] = 0.0f; ws[1] = 0.0f; ws[2] = 0.0f; ws[3] = 0.0f;
}

__device__ __forceinline__ int clampD(int s) {
    return s < 0 ? 0 : (s > DIM_D - 1 ? DIM_D - 1 : s);
}

__device__ __forceinline__ u32 pkf16(float a, float b) {
    return __builtin_bit_cast(u32, __builtin_amdgcn_cvt_pkrtz(a, b));
}

struct S2 { float I0, T0, II0, TT0, IT0, I1, T1, II1, TT1, IT1; };

__global__ __launch_bounds__(256)
void lncc3d_kernel(const float* __restrict__ I,
                   const float* __restrict__ T,
                   const float* __restrict__ zsrc,
                   float* __restrict__ out)
{
    // pair-buffered slice regions: [buf][slice][field][1024 words]; 24-word rows
    // (stage-1 phase (4r x 4g) hits quad (6r+g+c) mod 8 exactly twice = free)
    __shared__ __align__(16) float sR[2][2][2][1024];
    // W-sums f16-packed {pk(I,T),pk(II,TT)}: [slice][row][cell], col rot (c+r)&15
    __shared__ __align__(16) uint2 wA[2][RH][16];
    // W-sums IT f32, transposed [slice][w][row], stride 44
    __shared__ __align__(16) float wB[2][16][44];
    __shared__ float red[4];

    const int tid  = threadIdx.x;
    const int lane = tid & 63;
    const int wid  = tid >> 6;
    const int wo   = tid & 15;
    const int hb   = (tid >> 4) << 1;

    const int bw = blockIdx.x, bh = blockIdx.y, bz = blockIdx.z;
    const int b  = bz / NCH;
    const int c  = bz - b * NCH;
    const int w0 = bw * TW, h0 = bh * TH, d0 = c * CH;
    const int dEnd = min(d0 + CH, DIM_D);

    const int plane = DIM_H * DIM_W;
    const float* Ib = I + (size_t)b * DIM_D * plane;
    const float* Tb = T + (size_t)b * DIM_D * plane;

    // stage-1 jobs: job0 = tid (0..255), job1 = tid+256 (tid<64 only); 320 total
    const int  sl0  = (tid >= 160) ? 1 : 0;
    const int  rem0 = tid - (sl0 ? 160 : 0);
    const int  r0   = rem0 >> 2, g0 = rem0 & 3;
    const bool has2 = (tid < 64);
    const int  r1   = 24 + (tid >> 2), g1 = tid & 3;   // always slice 1

    // glds roles: wave = (slice, field); 4 chunks of 64x16B each
    const int stg_sl  = wid >> 1;
    const int stg_fld = wid & 1;
    const float* Fbg = (stg_fld ? Tb : Ib);
    int goff[4];
#pragma unroll
    for (int k = 0; k < 4; ++k) {
        const int s16 = k * 64 + lane;
        const int row = s16 / 6;
        const int q   = s16 - row * 6;
        const int gh  = h0 - 4 + row;
        const int gw  = w0 - 4 + (q << 2);
        goff[k] = (row < RH && gh >= 0 && gh < DIM_H && gw >= 0 && gw <= DIM_W - 4)
                  ? (gh * DIM_W + gw) : -1;
    }

    auto issue = [&](int spair, int buf) {   // stages this wave's slice of the pair
        const int sc = clampD(spair + stg_sl);
        const float* Fs = Fbg + (size_t)sc * plane;
#pragma unroll
        for (int k = 0; k < 4; ++k) {
            const float* gp = (goff[k] >= 0) ? (Fs + goff[k]) : zsrc;
            __builtin_amdgcn_global_load_lds((gu32*)gp,
                (lu32*)&sR[buf][stg_sl][stg_fld][k << 8], 16, 0, 0);
        }
    };

    auto st1 = [&](int buf, int sl, int r, int g) {
        const int c0 = g << 2;
        const float* rIp = &sR[buf][sl][0][r * RWDS];
        const float* rTp = &sR[buf][sl][1][r * RWDS];
        const float4 ia  = *(const float4*)(rIp + c0);
        const float4 ib4 = *(const float4*)(rIp + c0 + 4);
        const float4 ic4 = *(const float4*)(rIp + c0 + 8);
        const float4 ta  = *(const float4*)(rTp + c0);
        const float4 tb4 = *(const float4*)(rTp + c0 + 4);
        const float4 tc4 = *(const float4*)(rTp + c0 + 8);
        const float iv[12] = {ia.x, ia.y, ia.z, ia.w, ib4.x, ib4.y, ib4.z, ib4.w,
                              ic4.x, ic4.y, ic4.z, ic4.w};
        const float tv[12] = {ta.x, ta.y, ta.z, ta.w, tb4.x, tb4.y, tb4.z, tb4.w,
                              tc4.x, tc4.y, tc4.z, tc4.w};
        float aI = 0.f, aT = 0.f, aII = 0.f, aTT = 0.f, aIT = 0.f;
#pragma unroll
        for (int k = 0; k < 9; ++k) {
            aI += iv[k]; aT += tv[k];
            aII = fmaf(iv[k], iv[k], aII);
            aTT = fmaf(tv[k], tv[k], aTT);
            aIT = fmaf(iv[k], tv[k], aIT);
        }
        wA[sl][r][(c0 + r) & 15] = make_uint2(pkf16(aI, aT), pkf16(aII, aTT));
        wB[sl][c0][r] = aIT;
#pragma unroll
        for (int q = 1; q < 4; ++q) {
            const float ni = iv[8 + q], oi = iv[q - 1];
            const float nt = tv[8 + q], ot = tv[q - 1];
            aI += ni - oi; aT += nt - ot;
            aII = fmaf(ni, ni, fmaf(oi, -oi, aII));
            aTT = fmaf(nt, nt, fmaf(ot, -ot, aTT));
            aIT = fmaf(ni, nt, fmaf(oi, -ot, aIT));
            wA[sl][r][(c0 + q + r) & 15] = make_uint2(pkf16(aI, aT), pkf16(aII, aTT));
            wB[sl][c0 + q][r] = aIT;
        }
    };

    auto st2 = [&](int sl, bool vsx) -> S2 {
        S2 o;
        if (vsx) {
            const uint2 C0 = wA[sl][hb][(wo + hb) & 15];
            const h2 A0a = __builtin_bit_cast(h2, C0.x);
            const h2 A0b = __builtin_bit_cast(h2, C0.y);
            h2 SA = A0a, SB = A0b;
#pragma unroll
            for (int k = 1; k < 9; ++k) {
                const uint2 Ck = wA[sl][hb + k][(wo + hb + k) & 15];
                SA += __builtin_bit_cast(h2, Ck.x);
                SB += __builtin_bit_cast(h2, Ck.y);
            }
            const uint2 C9 = wA[sl][hb + 9][(wo + hb + 9) & 15];
            const h2 P1A = SA - A0a + __builtin_bit_cast(h2, C9.x);
            const h2 P1B = SB - A0b + __builtin_bit_cast(h2, C9.y);
            o.I0 = (float)SA.x;  o.T0 = (float)SA.y;
            o.II0 = (float)SB.x; o.TT0 = (float)SB.y;
            o.I1 = (float)P1A.x; o.T1 = (float)P1A.y;
            o.II1 = (float)P1B.x; o.TT1 = (float)P1B.y;
            const float2 B0 = *(const float2*)&wB[sl][wo][hb];
            const float2 B1 = *(const float2*)&wB[sl][wo][hb + 2];
            const float2 B2 = *(const float2*)&wB[sl][wo][hb + 4];
            const float2 B3 = *(const float2*)&wB[sl][wo][hb + 6];
            const float2 B4 = *(const float2*)&wB[sl][wo][hb + 8];
            o.IT0 = B0.x + B0.y + B1.x + B1.y + B2.x + B2.y + B3.x + B3.y + B4.x;
            o.IT1 = o.IT0 - B0.x + B4.y;
        } else {
            o.I0 = o.T0 = o.II0 = o.TT0 = o.IT0 = 0.f;
            o.I1 = o.T1 = o.II1 = o.TT1 = o.IT1 = 0.f;
        }
        return o;
    };

    // D-rings (static slot) + running sums, 5 fields x 2 px
    float rgI[2][9], rgT[2][9], rgII[2][9], rgTT[2][9], rgIT[2][9];
    float rnI[2], rnT[2], rnII[2], rnTT[2], rnIT[2];
#pragma unroll
    for (int p = 0; p < 2; ++p) {
        rnI[p] = rnT[p] = rnII[p] = rnTT[p] = rnIT[p] = 0.0f;
#pragma unroll
        for (int q = 0; q < 9; ++q) {
            rgI[p][q] = rgT[p][q] = rgII[p][q] = rgTT[p][q] = rgIT[p][q] = 0.0f;
        }
    }
    float acc = 0.0f;
    const int sStart = d0 - 4;

    // ---- prologue: pair0 -> buf0, pair1 -> buf1; certify pair0 ----
    issue(sStart, 0);
    issue(sStart + 2, 1);
    asm volatile("s_waitcnt vmcnt(4)" ::: "memory");
    __builtin_amdgcn_s_barrier();

#define RING(S, J, EM) { \
    rnI[0]  += S.I0  - rgI[0][J];  rgI[0][J]  = S.I0; \
    rnT[0]  += S.T0  - rgT[0][J];  rgT[0][J]  = S.T0; \
    rnII[0] += S.II0 - rgII[0][J]; rgII[0][J] = S.II0; \
    rnTT[0] += S.TT0 - rgTT[0][J]; rgTT[0][J] = S.TT0; \
    rnIT[0] += S.IT0 - rgIT[0][J]; rgIT[0][J] = S.IT0; \
    rnI[1]  += S.I1  - rgI[1][J];  rgI[1][J]  = S.I1; \
    rnT[1]  += S.T1  - rgT[1][J];  rgT[1][J]  = S.T1; \
    rnII[1] += S.II1 - rgII[1][J]; rgII[1][J] = S.II1; \
    rnTT[1] += S.TT1 - rgTT[1][J]; rgTT[1][J] = S.TT1; \
    rnIT[1] += S.IT1 - rgIT[1][J]; rgIT[1][J] = S.IT1; \
    if (EM) { \
        float cr, vv, tvv; \
        cr  = rnIT[0] - rnI[0] * rnT[0] * INV_K; \
        vv  = rnII[0] - rnI[0] * rnI[0] * INV_K; \
        tvv = rnTT[0] - rnT[0] * rnT[0] * INV_K; \
        acc += cr * cr * __builtin_amdgcn_rcpf(fmaf(tvv, vv, 1e-5f)); \
        cr  = rnIT[1] - rnI[1] * rnT[1] * INV_K; \
        vv  = rnII[1] - rnI[1] * rnI[1] * INV_K; \
        tvv = rnTT[1] - rnT[1] * rnT[1] * INV_K; \
        acc += cr * cr * __builtin_amdgcn_rcpf(fmaf(tvv, vv, 1e-5f)); \
    } }

#define PAIR(PP, J0, J1, BUF) { \
    const int sA = sStart + 2 * (PP); \
    const int sB = sA + 1; \
    const bool vsA = (sA >= 0) && (sA < DIM_D); \
    const bool vsB = (sB >= 0) && (sB < DIM_D); \
    const bool v0 = sl0 ? vsB : vsA; \
    if (v0) st1((BUF), sl0, r0, g0); \
    if (has2 && vsB) st1((BUF), 1, r1, g1); \
    asm volatile("s_waitcnt lgkmcnt(0)" ::: "memory"); \
    __builtin_amdgcn_s_barrier(); \
    issue(sA + 4, (BUF)); \
    { \
        const S2 sa = st2(0, vsA); \
        const S2 sb = st2(1, vsB); \
        const bool emA = (sA >= d0 + 4) && ((sA - 4) < dEnd); \
        const bool emB = (sB >= d0 + 4) && ((sB - 4) < dEnd); \
        RING(sa, J0, emA); \
        RING(sb, J1, emB); \
    } \
    asm volatile("s_waitcnt lgkmcnt(0)" ::: "memory"); \
    asm volatile("s_waitcnt vmcnt(4)" ::: "memory"); \
    __builtin_amdgcn_s_barrier(); \
}

    PAIR(0,  0, 1, 0)  PAIR(1,  2, 3, 1)  PAIR(2,  4, 5, 0)  PAIR(3,  6, 7, 1)
    PAIR(4,  8, 0, 0)  PAIR(5,  1, 2, 1)  PAIR(6,  3, 4, 0)  PAIR(7,  5, 6, 1)
    PAIR(8,  7, 8, 0)  PAIR(9,  0, 1, 1)  PAIR(10, 2, 3, 0)  PAIR(11, 4, 5, 1)
    PAIR(12, 6, 7, 0)  PAIR(13, 8, 0, 1)

#undef PAIR
#undef RING

    // drain any in-flight glds before exit/reduction
    asm volatile("s_waitcnt vmcnt(0)" ::: "memory");

    // ---- block reduction ----
#pragma unroll
    for (int off = 32; off > 0; off >>= 1) acc += __shfl_down(acc, off, 64);
    if (lane == 0) red[wid] = acc;
    __syncthreads();
    if (tid == 0) {
        const float bs = red[0] + red[1] + red[2] + red[3];
        atomicAdd(out, bs * (float)(-1.0 / NTOT));
    }
}

extern "C" void kernel_launch(void* const* d_in, const int* in_sizes, int n_in,
                              void* d_out, int out_size, void* d_ws, size_t ws_size,
                              hipStream_t stream) {
    const float* I = (const float*)d_in[0];
    const float* T = (const float*)d_in[1];
    float* out = (float*)d_out;
    float* ws  = (float*)d_ws;

    init_kernel<<<dim3(1), dim3(1), 0, stream>>>(out, ws);

    dim3 grid(DIM_W / TW, DIM_H / TH, DIM_B * NCH); // 10 x 6 x 18 = 1080
    dim3 block(256);
    lncc3d_kernel<<<grid, block, 0, stream>>>(I, T, ws, out);
}